// Round 2
// 113.412 us; speedup vs baseline: 1.0409x; 1.0409x over previous
//
#include <hip/hip_runtime.h>
#include <hip/hip_bf16.h>
#include <math.h>

// Problem constants (B, N, D_IN, H, F) = (2, 2048, 512, 8, 64)
#define Bq   2
#define Nq   2048
#define DIN  512
#define Hq   8
#define Fq   64
#define NEG  0.2f

using short8 = __attribute__((ext_vector_type(8))) short;   // 8 bf16 (4 VGPRs)
using f32x4  = __attribute__((ext_vector_type(4))) float;   // MFMA C/D

__device__ inline unsigned int bf16_rne(float x) {
    unsigned int u = __float_as_uint(x);
    u += 0x7fffu + ((u >> 16) & 1u);
    return u >> 16;
}

// ---------------------------------------------------------------------------
// Kernel 1 (prep): afrag (256 blocks) + wfrag (128 blocks), R8-validated.
// ---------------------------------------------------------------------------
#define AFRAG_BLOCKS 256
#define WFRAG_BLOCKS 128

__global__ __launch_bounds__(256) void prep_kernel(
    const float* __restrict__ nodes, ushort* __restrict__ Afrag,
    const float* __restrict__ W,     ushort* __restrict__ Wfrag)
{
    __shared__ __align__(16) char smem[16 * 516 * 4];   // 33 KB: max(As, Ws)
    const int bid = blockIdx.x;
    const int t   = threadIdx.x;

    if (bid < AFRAG_BLOCKS) {
        float (*As)[516] = (float(*)[516])smem;
        const int mt = bid;
        {
            const int row = t >> 4, c = t & 15;
#pragma unroll
            for (int i = 0; i < 8; i++) {
                float4 v = *(const float4*)&nodes[((size_t)mt * 16 + row) * DIN + (c + i * 16) * 4];
                *(float4*)&As[row][(c + i * 16) * 4] = v;
            }
        }
        __syncthreads();
        const int lane = t & 63, ksg = t >> 6;
        const int quad = lane >> 4, l15 = lane & 15;
#pragma unroll
        for (int k2 = 0; k2 < 4; k2++) {
            int ks = ksg * 4 + k2;
            const float* src = &As[l15][ks * 32 + quad * 8];
            float4 f0 = *(const float4*)src;
            float4 f1 = *(const float4*)(src + 4);
            uint4 pk;
            pk.x = bf16_rne(f0.x) | (bf16_rne(f0.y) << 16);
            pk.y = bf16_rne(f0.z) | (bf16_rne(f0.w) << 16);
            pk.z = bf16_rne(f1.x) | (bf16_rne(f1.y) << 16);
            pk.w = bf16_rne(f1.z) | (bf16_rne(f1.w) << 16);
            *(uint4*)(Afrag + ((size_t)(mt * 16 + ks) * 64 + lane) * 8) = pk;
        }
        return;
    }

    {
        float (*Ws)[68] = (float(*)[68])smem;
        const int id = bid - AFRAG_BLOCKS;
        const int ks = id & 15, h = id >> 4;
        {
            const int row = t >> 3, c = t & 7;
            const float* src = &W[(size_t)(ks * 32 + row) * (Hq * Fq) + h * 64 + c * 8];
            float4 v0 = *(const float4*)src;
            float4 v1 = *(const float4*)(src + 4);
            *(float4*)&Ws[row][c * 8]     = v0;
            *(float4*)&Ws[row][c * 8 + 4] = v1;
        }
        __syncthreads();
        const int lane = t & 63, nf = t >> 6;
        const int quad = lane >> 4, l15 = lane & 15;
        float f[8];
#pragma unroll
        for (int jj = 0; jj < 8; jj++) f[jj] = Ws[quad * 8 + jj][nf * 16 + l15];
        uint4 pk;
        pk.x = bf16_rne(f[0]) | (bf16_rne(f[1]) << 16);
        pk.y = bf16_rne(f[2]) | (bf16_rne(f[3]) << 16);
        pk.z = bf16_rne(f[4]) | (bf16_rne(f[5]) << 16);
        pk.w = bf16_rne(f[6]) | (bf16_rne(f[7]) << 16);
        *(uint4*)(Wfrag + (((size_t)(h * 16 + ks) * 4 + nf) * 64 + lane) * 8) = pk;
    }
}

// ---------------------------------------------------------------------------
// Kernel 2 (work): gemm (blocks [0,512), R8-validated) + pack_edges.
// The el/er epilogue additionally stores E_t = exp(er) and F_t = exp(NEG*er).
// These let the attn kernel replace its per-(i,j) transcendental exp with
// cndmask+mul (leaky-relu exp factorizes per branch).
// ---------------------------------------------------------------------------
#define GEMM_BLOCKS 512
#define PACK_BLOCKS 1024   // B * 64 words * 2048 rows / 256 threads

__global__ __launch_bounds__(256) void work_kernel(
    const ushort* __restrict__ Afrag, const ushort* __restrict__ Wfrag,
    const float*  __restrict__ avec,
    ushort* __restrict__ Vfrag,      // [16 bh][64 s][4 nf][64 lane][8] bf16
    float* __restrict__ el_t,        // [16][2048]
    float* __restrict__ er_t,        // [16][2048]
    float* __restrict__ E_t,         // [16][2048]  exp(er)
    float* __restrict__ F_t,         // [16][2048]  exp(NEG*er)
    const int* __restrict__ edges, unsigned int* __restrict__ ebT)
{
    const int bid = blockIdx.x;
    const int t   = threadIdx.x;

    if (bid >= GEMM_BLOCKS) {
        // ---- pack edges -> transposed bitmask ebT[b][jword(64)][i(2048)] ----
        int gid = (bid - GEMM_BLOCKS) * 256 + t;   // 0..262143
        int i = gid & 2047;
        int w = (gid >> 11) & 63;
        int b = gid >> 17;
        const int4* ep = (const int4*)(edges + (((size_t)b * Nq + i) * Nq + w * 32));
        unsigned int word = 0;
#pragma unroll
        for (int c = 0; c < 8; c++) {
            int4 v = ep[c];
            word |= (v.x != 0 ? 1u : 0u) << (c * 4);
            word |= (v.y != 0 ? 1u : 0u) << (c * 4 + 1);
            word |= (v.z != 0 ? 1u : 0u) << (c * 4 + 2);
            word |= (v.w != 0 ? 1u : 0u) << (c * 4 + 3);
        }
        ebT[((size_t)b * 64 + w) * Nq + i] = word;
        return;
    }

    // ---- gemm: R8-validated body ----
    const int lane = t & 63;
    const int wv   = t >> 6;
    const int quad = lane >> 4;
    const int l15  = lane & 15;
    const int h    = bid >> 6;            // 0..7
    const int mt   = (bid & 63) * 4 + wv; // 0..255
    const int row0 = mt * 16;

    const ushort* ap = Afrag + (size_t)mt * 8192 + lane * 8;   // + ks*512
    const ushort* bp = Wfrag + (size_t)h * 32768 + lane * 8;   // + ks*2048 + nf*512

    f32x4 zero4 = {0.f, 0.f, 0.f, 0.f};
    f32x4 acc[4] = {zero4, zero4, zero4, zero4};

    short8 a0, a1, b0[4], b1[4];
    a0 = *(const short8*)(ap);
#pragma unroll
    for (int nf = 0; nf < 4; nf++) b0[nf] = *(const short8*)(bp + nf * 512);

    for (int ks = 0; ks < 16; ks += 2) {
        a1 = *(const short8*)(ap + (ks + 1) * 512);
#pragma unroll
        for (int nf = 0; nf < 4; nf++) b1[nf] = *(const short8*)(bp + (ks + 1) * 2048 + nf * 512);
#pragma unroll
        for (int nf = 0; nf < 4; nf++)
            acc[nf] = __builtin_amdgcn_mfma_f32_16x16x32_bf16(a0, b0[nf], acc[nf], 0, 0, 0);
        a0 = *(const short8*)(ap + (ks + 2) * 512);   // ks=14 -> past end: lands in Wfrag, unused
#pragma unroll
        for (int nf = 0; nf < 4; nf++) b0[nf] = *(const short8*)(bp + (ks + 2) * 2048 + nf * 512);
#pragma unroll
        for (int nf = 0; nf < 4; nf++)
            acc[nf] = __builtin_amdgcn_mfma_f32_16x16x32_bf16(a1, b1[nf], acc[nf], 0, 0, 0);
    }

    // ---- fused el/er (+ exp tables) ----
    float aL[4], aR[4];
#pragma unroll
    for (int nf = 0; nf < 4; nf++) {
        aL[nf] = avec[nf * 16 + l15];
        aR[nf] = avec[Fq + nf * 16 + l15];
    }
    const int bb = row0 >> 11;
    const int bh = bb * Hq + h;
#pragma unroll
    for (int r = 0; r < 4; r++) {
        float pl = acc[0][r] * aL[0] + acc[1][r] * aL[1] + acc[2][r] * aL[2] + acc[3][r] * aL[3];
        float pr = acc[0][r] * aR[0] + acc[1][r] * aR[1] + acc[2][r] * aR[2] + acc[3][r] * aR[3];
#pragma unroll
        for (int off = 1; off < 16; off <<= 1) {
            pl += __shfl_xor(pl, off, 64);
            pr += __shfl_xor(pr, off, 64);
        }
        if (l15 == 0) {
            int n = (row0 + quad * 4 + r) & (Nq - 1);
            el_t[(size_t)bh * Nq + n] = pl;
            er_t[(size_t)bh * Nq + n] = pr;
            E_t[(size_t)bh * Nq + n]  = __expf(pr);
            F_t[(size_t)bh * Nq + n]  = __expf(NEG * pr);
        }
    }

    // ---- Vfrag: C in attn B-fragment order (validated R3/R4/R7/R8) ----
    const int n_base = row0 & (Nq - 1);
    const int sblk   = n_base >> 5;
    const int quadp  = ((wv & 1) << 1) | (quad >> 1);
    const int jj0    = (quad & 1) * 4;
#pragma unroll
    for (int nf = 0; nf < 4; nf++) {
        unsigned int r0 = bf16_rne(acc[nf][0]), r1 = bf16_rne(acc[nf][1]);
        unsigned int r2 = bf16_rne(acc[nf][2]), r3 = bf16_rne(acc[nf][3]);
        uint2 pk;
        pk.x = r0 | (r1 << 16);
        pk.y = r2 | (r3 << 16);
        size_t off = ((((size_t)bh * 64 + sblk) * 4 + nf) * 64 + quadp * 16 + l15) * 8 + jj0;
        *(uint2*)(Vfrag + off) = pk;
    }
}

// ---------------------------------------------------------------------------
// Kernel 3: MFMA attention (R8-validated structure) + inline ermax.
// Per-(i,j) exp replaced by factorized form:
//   score = leaky(el_i + er_j);  P = exp(score - m_i)
//   el+er > 0 :  P = exp(el_i - m_i)        * exp(er_j)      = A * E_j
//   el+er <= 0:  P = exp(NEG*el_i - m_i)    * exp(NEG*er_j)  = C * F_j
//   branch test: er_j > -el_i  <=>  E_j > exp(-el_i) = T   (exp monotone)
// jj body: cmp + 2 cndmask + mul per row-set, ZERO transcendentals.
// ---------------------------------------------------------------------------
__global__ __launch_bounds__(256) void attn_kernel(
    const float* __restrict__ el_t, const float* __restrict__ er_t,
    const float* __restrict__ E_t,  const float* __restrict__ F_t,
    const ushort* __restrict__ Vfrag,
    const unsigned int* __restrict__ ebT, float* __restrict__ attn)
{
    const int lane = threadIdx.x & 63;
    const int kh   = threadIdx.x >> 6;     // K-split index 0..3
    const int quad = lane >> 4;
    const int l15  = lane & 15;
    const int bid  = blockIdx.x;           // B*H*64 = 1024
    const int it   = bid & 63;
    const int h    = (bid >> 6) & 7;
    const int b    = bid >> 9;
    const int bh   = b * Hq + h;
    const int i0   = it * 32;

    // ---- inline ermax over er_t[bh][:] ----
    __shared__ float smax[4];
    const float* errow = er_t + (size_t)bh * Nq;
    float mx = -INFINITY;
#pragma unroll
    for (int ii = 0; ii < 8; ii++) mx = fmaxf(mx, errow[threadIdx.x + ii * 256]);
#pragma unroll
    for (int off = 32; off > 0; off >>= 1) mx = fmaxf(mx, __shfl_xor(mx, off, 64));
    if (lane == 0) smax[kh] = mx;
    __syncthreads();
    const float emax = fmaxf(fmaxf(smax[0], smax[1]), fmaxf(smax[2], smax[3]));

    const float elv0 = el_t[(size_t)bh * Nq + i0 + l15];
    const float elv1 = el_t[(size_t)bh * Nq + i0 + 16 + l15];
    const float xm0 = elv0 + emax, xm1 = elv1 + emax;
    const float m0 = fmaxf(xm0, NEG * xm0);    // safe shift: s - m <= 0
    const float m1 = fmaxf(xm1, NEG * xm1);
    // factorized coefficients (per row)
    const float A0 = __expf(elv0 - m0),       A1 = __expf(elv1 - m1);
    const float C0 = __expf(NEG * elv0 - m0), C1 = __expf(NEG * elv1 - m1);
    const float T0 = __expf(-elv0),           T1 = __expf(-elv1);

    const float*        Ep  = E_t + (size_t)bh * Nq + kh * 512;          // + s*32
    const float*        Fp  = F_t + (size_t)bh * Nq + kh * 512;          // + s*32
    const ushort*       vp  = Vfrag + (size_t)bh * 131072 + kh * 32768 + lane * 8; // + s*2048
    const unsigned int* e0p = ebT + ((size_t)b * 64 + kh * 16) * Nq + i0 + l15;    // + s*2048

    f32x4 zero4 = {0.f, 0.f, 0.f, 0.f};
    f32x4 acc0[4] = {zero4, zero4, zero4, zero4};
    f32x4 acc1[4] = {zero4, zero4, zero4, zero4};
    float l0 = 0.f, l1 = 0.f;

    for (int s = 0; s < 16; s++) {
        short8 vb0 = *(const short8*)(vp + s * 2048);
        short8 vb1 = *(const short8*)(vp + s * 2048 + 512);
        short8 vb2 = *(const short8*)(vp + s * 2048 + 1024);
        short8 vb3 = *(const short8*)(vp + s * 2048 + 1536);
        unsigned int w0 = e0p[(size_t)s * Nq];
        unsigned int w1 = e0p[(size_t)s * Nq + 16];
        float4 Ea = *(const float4*)(Ep + s * 32 + quad * 8);
        float4 Eb = *(const float4*)(Ep + s * 32 + quad * 8 + 4);
        float4 Fa = *(const float4*)(Fp + s * 32 + quad * 8);
        float4 Fb = *(const float4*)(Fp + s * 32 + quad * 8 + 4);

        const unsigned int wq0 = w0 >> (quad * 8);
        const unsigned int wq1 = w1 >> (quad * 8);
        float E8[8] = {Ea.x, Ea.y, Ea.z, Ea.w, Eb.x, Eb.y, Eb.z, Eb.w};
        float F8[8] = {Fa.x, Fa.y, Fa.z, Fa.w, Fb.x, Fb.y, Fb.z, Fb.w};

        union { short8 s8; unsigned int w[4]; } af0, af1;
#pragma unroll
        for (int pp = 0; pp < 4; pp++) {
            unsigned int ua0, ub0, ua1, ub1;
#pragma unroll
            for (int q2 = 0; q2 < 2; q2++) {
                const int jj = pp * 2 + q2;
                float e  = E8[jj];
                float fv = F8[jj];
                float s0 = (e > T0) ? A0 : C0;
                float v0 = (e > T0) ? e  : fv;
                float s1 = (e > T1) ? A1 : C1;
                float v1 = (e > T1) ? e  : fv;
                float p0 = s0 * v0;
                float p1 = s1 * v1;
                int k0 = ((int)(wq0 << (31 - jj))) >> 31;
                int k1 = ((int)(wq1 << (31 - jj))) >> 31;
                unsigned int m0b = __float_as_uint(p0) & (unsigned int)k0;
                unsigned int m1b = __float_as_uint(p1) & (unsigned int)k1;
                l0 += __uint_as_float(m0b);
                l1 += __uint_as_float(m1b);
                if (q2 == 0) { ua0 = m0b; ua1 = m1b; }
                else         { ub0 = m0b; ub1 = m1b; }
            }
            af0.w[pp] = __builtin_amdgcn_perm(ub0, ua0, 0x07060302);
            af1.w[pp] = __builtin_amdgcn_perm(ub1, ua1, 0x07060302);
        }

        acc0[0] = __builtin_amdgcn_mfma_f32_16x16x32_bf16(af0.s8, vb0, acc0[0], 0, 0, 0);
        acc1[0] = __builtin_amdgcn_mfma_f32_16x16x32_bf16(af1.s8, vb0, acc1[0], 0, 0, 0);
        acc0[1] = __builtin_amdgcn_mfma_f32_16x16x32_bf16(af0.s8, vb1, acc0[1], 0, 0, 0);
        acc1[1] = __builtin_amdgcn_mfma_f32_16x16x32_bf16(af1.s8, vb1, acc1[1], 0, 0, 0);
        acc0[2] = __builtin_amdgcn_mfma_f32_16x16x32_bf16(af0.s8, vb2, acc0[2], 0, 0, 0);
        acc1[2] = __builtin_amdgcn_mfma_f32_16x16x32_bf16(af1.s8, vb2, acc1[2], 0, 0, 0);
        acc0[3] = __builtin_amdgcn_mfma_f32_16x16x32_bf16(af0.s8, vb3, acc0[3], 0, 0, 0);
        acc1[3] = __builtin_amdgcn_mfma_f32_16x16x32_bf16(af1.s8, vb3, acc1[3], 0, 0, 0);
    }

    // ---- combine 4 K-splits via LDS (validated R4/R7/R8) ----
    __shared__ float lds_acc[3][32][64];
    __shared__ float lds_l[3][2][64];
    if (kh > 0) {
#pragma unroll
        for (int nf = 0; nf < 4; nf++)
#pragma unroll
            for (int r = 0; r < 4; r++) {
                lds_acc[kh - 1][nf * 4 + r][lane]      = acc0[nf][r];
                lds_acc[kh - 1][16 + nf * 4 + r][lane] = acc1[nf][r];
            }
        lds_l[kh - 1][0][lane] = l0;
        lds_l[kh - 1][1][lane] = l1;
    }
    __syncthreads();
    if (kh == 0) {
#pragma unroll
        for (int q = 0; q < 3; q++) {
#pragma unroll
            for (int nf = 0; nf < 4; nf++)
#pragma unroll
                for (int r = 0; r < 4; r++) {
                    acc0[nf][r] += lds_acc[q][nf * 4 + r][lane];
                    acc1[nf][r] += lds_acc[q][16 + nf * 4 + r][lane];
                }
            l0 += lds_l[q][0][lane];
            l1 += lds_l[q][1][lane];
        }
        l0 += __shfl_xor(l0, 16, 64);
        l0 += __shfl_xor(l0, 32, 64);
        l1 += __shfl_xor(l1, 16, 64);
        l1 += __shfl_xor(l1, 32, 64);
        float lr0[4], lr1[4];
#pragma unroll
        for (int r = 0; r < 4; r++) {
            lr0[r] = __shfl(l0, quad * 4 + r, 64);
            lr1[r] = __shfl(l1, quad * 4 + r, 64);
        }
#pragma unroll
        for (int nf = 0; nf < 4; nf++)
#pragma unroll
            for (int r = 0; r < 4; r++) {
                attn[(((size_t)b * Nq + i0 + quad * 4 + r) * Hq + h) * Fq + nf * 16 + l15] =
                    acc0[nf][r] / lr0[r];
                attn[(((size_t)b * Nq + i0 + 16 + quad * 4 + r) * Hq + h) * Fq + nf * 16 + l15] =
                    acc1[nf][r] / lr1[r];
            }
    }
}

// ---------------------------------------------------------------------------
// Kernel 4: out[b,i,f] = sigmoid( mean_h attn[b,i,h,f] )
// ---------------------------------------------------------------------------
__global__ __launch_bounds__(256) void out_kernel(
    const float* __restrict__ attn, float* __restrict__ out)
{
    const int idx = blockIdx.x * 256 + threadIdx.x;
    const int f   = idx & 63;
    const int bn  = idx >> 6;
    const float* p = attn + (size_t)bn * Hq * Fq + f;
    float s = 0.f;
#pragma unroll
    for (int h = 0; h < Hq; h++) s += p[h * Fq];
    s *= (1.f / Hq);
    out[idx] = 1.f / (1.f + __expf(-s));
}

// ---------------------------------------------------------------------------
extern "C" void kernel_launch(void* const* d_in, const int* in_sizes, int n_in,
                              void* d_out, int out_size, void* d_ws, size_t ws_size,
                              hipStream_t stream) {
    const float* nodes = (const float*)d_in[0];   // (2,2048,512)
    const int*   edges = (const int*)d_in[1];     // (2,2048,2048,1)
    const float* W     = (const float*)d_in[2];   // (512,512)
    const float* a     = (const float*)d_in[3];   // (128,)
    float* out = (float*)d_out;                   // (2,2048,64)

    char* ws = (char*)d_ws;
    ushort* Afrag = (ushort*)ws;           ws += (size_t)Bq * Nq * DIN * 2;           // 4 MB
    ushort* Wfrag = (ushort*)ws;           ws += (size_t)DIN * Hq * Fq * 2;           // 512 KB
    ushort* Vfrag = (ushort*)ws;           ws += (size_t)Bq * Hq * Nq * Fq * 2;       // 4 MB
    float*  el_t  = (float*)ws;            ws += (size_t)Bq * Hq * Nq * 4;            // 128 KB
    float*  er_t  = (float*)ws;            ws += (size_t)Bq * Hq * Nq * 4;            // 128 KB
    float*  E_t   = (float*)ws;            ws += (size_t)Bq * Hq * Nq * 4;            // 128 KB
    float*  F_t   = (float*)ws;            ws += (size_t)Bq * Hq * Nq * 4;            // 128 KB
    unsigned int* ebT = (unsigned int*)ws; ws += (size_t)Bq * (Nq / 32) * Nq * 4;     // 1 MB
    float*  attn  = (float*)ws;                                                       // 8 MB

    prep_kernel<<<AFRAG_BLOCKS + WFRAG_BLOCKS, 256, 0, stream>>>(nodes, Afrag, W, Wfrag);
    work_kernel<<<GEMM_BLOCKS + PACK_BLOCKS, 256, 0, stream>>>(
        Afrag, Wfrag, a, Vfrag, el_t, er_t, E_t, F_t, edges, ebT);
    attn_kernel<<<Bq * Hq * (Nq / 64), 256, 0, stream>>>(el_t, er_t, E_t, F_t, Vfrag, ebT, attn);
    out_kernel<<<(Bq * Nq * Fq) / 256, 256, 0, stream>>>(attn, out);
}